// Round 1
// baseline (216.358 us; speedup 1.0000x reference)
//
#include <hip/hip_runtime.h>
#include <math.h>

#define NTH 256

// ---- workspace float offsets (all 16B-aligned where float4-read) ----
enum : int {
  WQ0_OFF = 0,        // [4][19][8]  = 608   (j<6: ak fold, j>=6: ok fold)
  WQ1_OFF = 608,      // [4][128][8] = 4096
  AO0_OFF = 4704,     // [4][9][128] = 4608  (i<7: nbv path, i>=7: ob path)
  B0_OFF  = 9312,     // 128
  AO1_OFF = 9440,     // [4][9][4]   = 144
  B1H_OFF = 9584,     // 4
  U0_OFF  = 9600,     // 512*128 = 65536   apw0 @ fpw0_top
  V0_OFF  = 75136,    // 65536             opw0 @ fpw0_bot
  F1T_OFF = 140672,   // 128*4 = 512       fpw1_top @ headw
  F1B_OFF = 141184,   // 512               fpw1_bot @ headw
  U1_OFF  = 141696,   // 512*4 = 2048      apw1 @ F1T
  V1_OFF  = 143744,   // 2048              opw1 @ F1B
  BB1_OFF = 145792,   // 128               apb1@fpw1_top + opb1@fpw1_bot + fpb1
  WS_END  = 145920
};

// ---------------- prep_a: direct folds + U0/V0/F1T/F1B/B0/bb1 ----------------
// flat output regions:
//   [0,608) WQ0 | [608,4704) WQ1 | [4704,70240) U0 | [70240,135776) V0
//   [135776,136288) F1T | [136288,136800) F1B | [136800,136928) B0 | [136928,137056) bb1
__global__ void prep_a(
    const float* __restrict__ wq0, const float* __restrict__ wak0, const float* __restrict__ wok0,
    const float* __restrict__ apw0, const float* __restrict__ opw0,
    const float* __restrict__ fpw0, const float* __restrict__ apb0, const float* __restrict__ opb0,
    const float* __restrict__ fpb0,
    const float* __restrict__ wq1, const float* __restrict__ wak1, const float* __restrict__ wok1,
    const float* __restrict__ apb1, const float* __restrict__ opb1, const float* __restrict__ fpb1,
    const float* __restrict__ fpw1, const float* __restrict__ headw,
    float* __restrict__ ws)
{
  int gid = blockIdx.x * NTH + threadIdx.x;
  if (gid < 608) {                                      // WQ0[h][r][j]
    int j = gid & 7, r = (gid >> 3) % 19, h = gid / (19 * 8);
    const float* wk = (j < 6) ? (wak0 + j * 512) : (wok0 + (j - 6) * 512);
    const float* a = wq0 + r * 512 + h * 128;
    const float* b = wk + h * 128;
    float acc = 0.f;
    for (int c = 0; c < 128; c++) acc += a[c] * b[c];
    ws[WQ0_OFF + gid] = acc;
  } else if (gid < 4704) {                              // WQ1[h][cc][j]
    int idx = gid - 608;
    int j = idx & 7, cc = (idx >> 3) & 127, h = idx >> 10;
    const float* wk = (j < 6) ? (wak1 + j * 512) : (wok1 + (j - 6) * 512);
    const float* a = wq1 + cc * 512 + h * 128;
    const float* b = wk + h * 128;
    float acc = 0.f;
    for (int c = 0; c < 128; c++) acc += a[c] * b[c];
    ws[WQ1_OFF + idx] = acc;
  } else if (gid < 70240) {                             // U0[r][j]
    int idx = gid - 4704;
    int j = idx & 127, r = idx >> 7;
    float acc = 0.f;
    for (int t = 0; t < 128; t++) acc += apw0[r * 128 + t] * fpw0[t * 128 + j];
    ws[U0_OFF + idx] = acc;
  } else if (gid < 135776) {                            // V0[r][j]
    int idx = gid - 70240;
    int j = idx & 127, r = idx >> 7;
    float acc = 0.f;
    for (int t = 0; t < 128; t++) acc += opw0[r * 128 + t] * fpw0[(128 + t) * 128 + j];
    ws[V0_OFF + idx] = acc;
  } else if (gid < 136288) {                            // F1T[i][o]
    int idx = gid - 135776;
    int o2 = idx & 3, i = idx >> 2;
    float acc = 0.f;
    for (int j = 0; j < 128; j++) acc += fpw1[i * 128 + j] * headw[j * 4 + o2];
    ws[F1T_OFF + idx] = acc;
  } else if (gid < 136800) {                            // F1B[i][o]
    int idx = gid - 136288;
    int o2 = idx & 3, i = idx >> 2;
    float acc = 0.f;
    for (int j = 0; j < 128; j++) acc += fpw1[(128 + i) * 128 + j] * headw[j * 4 + o2];
    ws[F1B_OFF + idx] = acc;
  } else if (gid < 136928) {                            // B0[j]
    int j = gid - 136800;
    float acc = fpb0[j];
    for (int c = 0; c < 128; c++)
      acc += apb0[c] * fpw0[c * 128 + j] + opb0[c] * fpw0[(128 + c) * 128 + j];
    ws[B0_OFF + j] = acc;
  } else if (gid < 137056) {                            // bb1[j]
    int j = gid - 136928;
    float acc = fpb1[j];
    for (int c = 0; c < 128; c++)
      acc += apb1[c] * fpw1[c * 128 + j] + opb1[c] * fpw1[(128 + c) * 128 + j];
    ws[BB1_OFF + j] = acc;
  }
}

// ---------------- prep_b: AO0 (needs U0/V0), U1/V1 (need F1T/F1B) ----------------
// regions: [0,4608) AO0 | [4608,6656) U1 | [6656,8704) V1
__global__ void prep_b(
    const float* __restrict__ wav0, const float* __restrict__ wov0,
    const float* __restrict__ apw1, const float* __restrict__ opw1,
    float* __restrict__ ws)
{
  int gid = blockIdx.x * NTH + threadIdx.x;
  if (gid < 4608) {                                     // AO0[h][i][j]
    int j = gid & 127, i = (gid >> 7) % 9, h = gid / 1152;
    float acc = 0.f;
    if (i < 7) {
      const float* w = wav0 + i * 512 + h * 128;
      const float* u = ws + U0_OFF + (h * 128) * 128 + j;
      for (int c = 0; c < 128; c++) acc += w[c] * u[c * 128];
    } else {
      const float* w = wov0 + (i - 7) * 512 + h * 128;
      const float* u = ws + V0_OFF + (h * 128) * 128 + j;
      for (int c = 0; c < 128; c++) acc += w[c] * u[c * 128];
    }
    ws[AO0_OFF + gid] = acc;
  } else if (gid < 6656) {                              // U1[r][o]
    int idx = gid - 4608;
    int o2 = idx & 3, r = idx >> 2;
    float acc = 0.f;
    for (int t = 0; t < 128; t++) acc += apw1[r * 128 + t] * ws[F1T_OFF + t * 4 + o2];
    ws[U1_OFF + idx] = acc;
  } else if (gid < 8704) {                              // V1[r][o]
    int idx = gid - 6656;
    int o2 = idx & 3, r = idx >> 2;
    float acc = 0.f;
    for (int t = 0; t < 128; t++) acc += opw1[r * 128 + t] * ws[F1B_OFF + t * 4 + o2];
    ws[V1_OFF + idx] = acc;
  }
}

// ---------------- prep_c: AO1 (needs U1/V1), B1H (needs bb1) ----------------
__global__ void prep_c(
    const float* __restrict__ wav1, const float* __restrict__ wov1,
    const float* __restrict__ headw, const float* __restrict__ headb,
    float* __restrict__ ws)
{
  int gid = threadIdx.x;
  if (gid < 144) {                                      // AO1[h][i][o]
    int o2 = gid & 3, i = (gid >> 2) % 9, h = gid / 36;
    float acc = 0.f;
    if (i < 7) {
      for (int c = 0; c < 128; c++)
        acc += wav1[i * 512 + h * 128 + c] * ws[U1_OFF + (h * 128 + c) * 4 + o2];
    } else {
      for (int c = 0; c < 128; c++)
        acc += wov1[(i - 7) * 512 + h * 128 + c] * ws[V1_OFF + (h * 128 + c) * 4 + o2];
    }
    ws[AO1_OFF + gid] = acc;
  } else if (gid < 148) {                               // B1H[o]
    int o2 = gid - 144;
    float acc = headb[o2];
    for (int j = 0; j < 128; j++) acc += ws[BB1_OFF + j] * headw[j * 4 + o2];
    ws[B1H_OFF + o2] = acc;
  }
}

// ---------------- main: 1 thread per sample ----------------
__global__ __launch_bounds__(256, 2) void actor_main(
    const float* __restrict__ obs, const float* __restrict__ ws,
    const float* __restrict__ pca0, const float* __restrict__ pco0,
    const float* __restrict__ pca1, const float* __restrict__ pco1,
    float* __restrict__ out, int n)
{
  __shared__ float sobs[NTH * 37];
  const int tid = threadIdx.x;
  const int m0 = blockIdx.x * NTH;
  int rows = n - m0; if (rows > NTH) rows = NTH;
  {
    const float* gsrc = obs + (size_t)m0 * 37;
    const int tot = rows * 37;
    for (int i = tid; i < tot; i += NTH) sobs[i] = gsrc[i];
  }
  __syncthreads();
  if (tid >= rows) return;

  const float* o = sobs + tid * 37;
  const float scale = 0.17677669529663687f;   // (C//H)^-0.5 = 1/sqrt(32)

  // ---- unpack features ----
  float qf[19];
#pragma unroll
  for (int i = 0; i < 12; i++) qf[i] = o[i];
#pragma unroll
  for (int i = 0; i < 7; i++) qf[12 + i] = o[30 + i];
  float nb[2][6];
#pragma unroll
  for (int k2 = 0; k2 < 2; k2++)
#pragma unroll
    for (int i = 0; i < 6; i++) nb[k2][i] = o[12 + 6 * k2 + i];
  const float nbv6[2] = { o[24], o[25] };
  const float obf[2][2] = { { o[26], o[27] }, { o[28], o[29] } };
  const float ax = o[0], ay = o[1];

  // ---- distances & decay weights (positions identical for both layers) ----
  float dista[2], disto[2];
#pragma unroll
  for (int k2 = 0; k2 < 2; k2++) {
    float dx = ax - nb[k2][0], dy = ay - nb[k2][1];
    dista[k2] = sqrtf(dx * dx + dy * dy);
    float ex = ax - obf[k2][0], ey = ay - obf[k2][1];
    disto[k2] = sqrtf(ex * ex + ey * ey);
  }
  const float ca0 = pca0[0], co0 = pco0[0], ca1 = pca1[0], co1 = pco1[0];
  float dwa0[2], dwo0[2], dwa1[2], dwo1[2];
#pragma unroll
  for (int k2 = 0; k2 < 2; k2++) {
    dwa0[k2] = __expf(-ca0 * dista[k2]);
    dwo0[k2] = __expf(-co0 * disto[k2]);
    dwa1[k2] = __expf(-ca1 * dista[k2]);
    dwo1[k2] = __expf(-co1 * disto[k2]);
  }

  // ---- layer 0: query-side fold t0[h][j]  (j<6: ak, j>=6: ok) ----
  float t0[4][8];
#pragma unroll
  for (int h = 0; h < 4; h++)
#pragma unroll
    for (int j = 0; j < 8; j++) t0[h][j] = 0.f;
  {
    const float4* WQ0v = (const float4*)(ws + WQ0_OFF);
#pragma unroll
    for (int h = 0; h < 4; h++) {
#pragma unroll
      for (int r = 0; r < 19; r++) {
        float q = qf[r];
        float4 w0 = WQ0v[(h * 19 + r) * 2 + 0];
        float4 w1 = WQ0v[(h * 19 + r) * 2 + 1];
        t0[h][0] += q * w0.x; t0[h][1] += q * w0.y; t0[h][2] += q * w0.z; t0[h][3] += q * w0.w;
        t0[h][4] += q * w1.x; t0[h][5] += q * w1.y; t0[h][6] += q * w1.z; t0[h][7] += q * w1.w;
      }
    }
  }

  // ---- layer 0: attention + weighted features wf[h][i] (i<7 nbv, i>=7 ob) ----
  float wf[4][9];
#pragma unroll
  for (int h = 0; h < 4; h++) {
    float la[2], lo[2];
#pragma unroll
    for (int k2 = 0; k2 < 2; k2++) {
      float da = t0[h][0] * nb[k2][0] + t0[h][1] * nb[k2][1] + t0[h][2] * nb[k2][2]
               + t0[h][3] * nb[k2][3] + t0[h][4] * nb[k2][4] + t0[h][5] * nb[k2][5];
      la[k2] = da * scale * dwa0[k2];
      float dof = t0[h][6] * obf[k2][0] + t0[h][7] * obf[k2][1];
      lo[k2] = dof * scale * dwo0[k2];
    }
    float e  = __expf(la[1] - la[0]); float aa1 = e  / (1.f + e);  float aa0 = 1.f - aa1;
    float eo = __expf(lo[1] - lo[0]); float bo1 = eo / (1.f + eo); float bo0 = 1.f - bo1;
#pragma unroll
    for (int i = 0; i < 6; i++) wf[h][i] = aa0 * nb[0][i] + aa1 * nb[1][i];
    wf[h][6] = aa0 * nbv6[0] + aa1 * nbv6[1];
    wf[h][7] = bo0 * obf[0][0] + bo1 * obf[1][0];
    wf[h][8] = bo0 * obf[0][1] + bo1 * obf[1][1];
  }

  // ---- layer 0: h1[j] = B0[j] + sum_{h,i} wf[h][i] * AO0[h][i][j] ----
  float h1[128];
  {
    const float4* B0v = (const float4*)(ws + B0_OFF);
#pragma unroll
    for (int j = 0; j < 32; j++) {
      float4 b = B0v[j];
      h1[4 * j] = b.x; h1[4 * j + 1] = b.y; h1[4 * j + 2] = b.z; h1[4 * j + 3] = b.w;
    }
    const float4* AO0v = (const float4*)(ws + AO0_OFF);
#pragma unroll
    for (int h = 0; h < 4; h++) {
#pragma unroll
      for (int i = 0; i < 9; i++) {
        float f = wf[h][i];
#pragma unroll
        for (int j = 0; j < 32; j++) {
          float4 w = AO0v[(h * 9 + i) * 32 + j];
          h1[4 * j]     += f * w.x;
          h1[4 * j + 1] += f * w.y;
          h1[4 * j + 2] += f * w.z;
          h1[4 * j + 3] += f * w.w;
        }
      }
    }
  }

  // ---- layer 1: query-side fold t1[h][j] ----
  float t1[4][8];
#pragma unroll
  for (int h = 0; h < 4; h++)
#pragma unroll
    for (int j = 0; j < 8; j++) t1[h][j] = 0.f;
  {
    const float4* WQ1v = (const float4*)(ws + WQ1_OFF);
#pragma unroll
    for (int c = 0; c < 128; c++) {
      float q = h1[c];
#pragma unroll
      for (int h = 0; h < 4; h++) {
        float4 w0 = WQ1v[(h * 128 + c) * 2 + 0];
        float4 w1 = WQ1v[(h * 128 + c) * 2 + 1];
        t1[h][0] += q * w0.x; t1[h][1] += q * w0.y; t1[h][2] += q * w0.z; t1[h][3] += q * w0.w;
        t1[h][4] += q * w1.x; t1[h][5] += q * w1.y; t1[h][6] += q * w1.z; t1[h][7] += q * w1.w;
      }
    }
  }

  // ---- layer 1: attention + weighted features ----
  float wf1[4][9];
#pragma unroll
  for (int h = 0; h < 4; h++) {
    float la[2], lo[2];
#pragma unroll
    for (int k2 = 0; k2 < 2; k2++) {
      float da = t1[h][0] * nb[k2][0] + t1[h][1] * nb[k2][1] + t1[h][2] * nb[k2][2]
               + t1[h][3] * nb[k2][3] + t1[h][4] * nb[k2][4] + t1[h][5] * nb[k2][5];
      la[k2] = da * scale * dwa1[k2];
      float dof = t1[h][6] * obf[k2][0] + t1[h][7] * obf[k2][1];
      lo[k2] = dof * scale * dwo1[k2];
    }
    float e  = __expf(la[1] - la[0]); float aa1 = e  / (1.f + e);  float aa0 = 1.f - aa1;
    float eo = __expf(lo[1] - lo[0]); float bo1 = eo / (1.f + eo); float bo0 = 1.f - bo1;
#pragma unroll
    for (int i = 0; i < 6; i++) wf1[h][i] = aa0 * nb[0][i] + aa1 * nb[1][i];
    wf1[h][6] = aa0 * nbv6[0] + aa1 * nbv6[1];
    wf1[h][7] = bo0 * obf[0][0] + bo1 * obf[1][0];
    wf1[h][8] = bo0 * obf[0][1] + bo1 * obf[1][1];
  }

  // ---- layer 1 + head (folded): out4 = B1H + sum wf1[h][i] * AO1[h][i][:] ----
  float4 acc = *(const float4*)(ws + B1H_OFF);
  {
    const float4* AO1v = (const float4*)(ws + AO1_OFF);
#pragma unroll
    for (int h = 0; h < 4; h++) {
#pragma unroll
      for (int i = 0; i < 9; i++) {
        float f = wf1[h][i];
        float4 w = AO1v[h * 9 + i];
        acc.x += f * w.x; acc.y += f * w.y; acc.z += f * w.z; acc.w += f * w.w;
      }
    }
  }
  ((float4*)out)[m0 + tid] = acc;
}

extern "C" void kernel_launch(void* const* d_in, const int* in_sizes, int n_in,
                              void* d_out, int out_size, void* d_ws, size_t ws_size,
                              hipStream_t stream)
{
  const float* obs  = (const float*)d_in[0];
  const float* wq0  = (const float*)d_in[1];
  const float* wak0 = (const float*)d_in[2];
  const float* wav0 = (const float*)d_in[3];
  const float* wok0 = (const float*)d_in[4];
  const float* wov0 = (const float*)d_in[5];
  const float* apw0 = (const float*)d_in[6];
  const float* apb0 = (const float*)d_in[7];
  const float* opw0 = (const float*)d_in[8];
  const float* opb0 = (const float*)d_in[9];
  const float* fpw0 = (const float*)d_in[10];
  const float* fpb0 = (const float*)d_in[11];
  const float* ca0  = (const float*)d_in[12];
  const float* co0  = (const float*)d_in[13];
  const float* wq1  = (const float*)d_in[14];
  const float* wak1 = (const float*)d_in[15];
  const float* wav1 = (const float*)d_in[16];
  const float* wok1 = (const float*)d_in[17];
  const float* wov1 = (const float*)d_in[18];
  const float* apw1 = (const float*)d_in[19];
  const float* apb1 = (const float*)d_in[20];
  const float* opw1 = (const float*)d_in[21];
  const float* opb1 = (const float*)d_in[22];
  const float* fpw1 = (const float*)d_in[23];
  const float* fpb1 = (const float*)d_in[24];
  const float* ca1  = (const float*)d_in[25];
  const float* co1  = (const float*)d_in[26];
  const float* headw = (const float*)d_in[27];
  const float* headb = (const float*)d_in[28];
  float* ws = (float*)d_ws;
  int n = in_sizes[0] / 37;

  prep_a<<<(137056 + NTH - 1) / NTH, NTH, 0, stream>>>(
      wq0, wak0, wok0, apw0, opw0, fpw0, apb0, opb0, fpb0,
      wq1, wak1, wok1, apb1, opb1, fpb1, fpw1, headw, ws);
  prep_b<<<(8704 + NTH - 1) / NTH, NTH, 0, stream>>>(wav0, wov0, apw1, opw1, ws);
  prep_c<<<1, NTH, 0, stream>>>(wav1, wov1, headw, headb, ws);
  actor_main<<<(n + NTH - 1) / NTH, NTH, 0, stream>>>(
      obs, ws, ca0, co0, ca1, co1, (float*)d_out, n);
}

// Round 2
// 175.191 us; speedup vs baseline: 1.2350x; 1.2350x over previous
//
#include <hip/hip_runtime.h>
#include <math.h>

#define NTH 256

// ============ workspace float offsets ============
// Final tables (contiguous, staged to LDS by actor_main): 1940 floats = 485 float4
enum : int {
  WQ0_OFF = 0,        // [4][19][8]  = 608
  M_OFF   = 608,      // [36][32]    = 1152   (AO0 @ WQ1fold)
  TB_OFF  = 1760,     // [4][8]      = 32     (B0 @ WQ1fold)
  AO1_OFF = 1792,     // [36][4]     = 144
  B1H_OFF = 1936,     // [4]         = 4
  TBL_N   = 1940,
  // intermediates
  WQ1_OFF = 1952,     // [4][128][8] = 4096
  AO0_OFF = 6048,     // [36][128]   = 4608
  PA0_OFF = 10656,    // [4][7][128] = 3584
  PO0_OFF = 14240,    // [4][2][128] = 1024
  PA1_OFF = 15264,    // 3584
  PO1_OFF = 18848,    // 1024
  F1T_OFF = 19872,    // [128][4] = 512   fpw1_top @ headw
  F1B_OFF = 20384,    // 512              fpw1_bot @ headw
  B0_OFF  = 20896,    // 128
  BB1_OFF = 21024,    // 128
  WS_END  = 21152
};

// ---------------- prep1: everything derivable from raw inputs ----------------
// [0,608) WQ0 | [608,4704) WQ1 | [4704,8288) P_a0 | [8288,9312) P_o0
// [9312,12896) P_a1 | [12896,13920) P_o1 | [13920,14432) F1T | [14432,14944) F1B
// [14944,15072) B0 | [15072,15200) bb1
__global__ void prep1(
    const float* __restrict__ wq0, const float* __restrict__ wak0, const float* __restrict__ wok0,
    const float* __restrict__ wq1, const float* __restrict__ wak1, const float* __restrict__ wok1,
    const float* __restrict__ wav0, const float* __restrict__ apw0,
    const float* __restrict__ wov0, const float* __restrict__ opw0,
    const float* __restrict__ wav1, const float* __restrict__ apw1,
    const float* __restrict__ wov1, const float* __restrict__ opw1,
    const float* __restrict__ fpw1, const float* __restrict__ headw,
    const float* __restrict__ fpw0,
    const float* __restrict__ fpb0, const float* __restrict__ apb0, const float* __restrict__ opb0,
    const float* __restrict__ fpb1, const float* __restrict__ apb1, const float* __restrict__ opb1,
    float* __restrict__ ws)
{
  int gid = blockIdx.x * NTH + threadIdx.x;
  if (gid < 608) {                                      // WQ0[h][r][j]
    int j = gid & 7, r = (gid >> 3) % 19, h = gid / 152;
    const float* a = wq0 + r * 512 + h * 128;
    const float* b = ((j < 6) ? (wak0 + j * 512) : (wok0 + (j - 6) * 512)) + h * 128;
    float acc = 0.f;
    for (int c = 0; c < 128; c++) acc += a[c] * b[c];
    ws[WQ0_OFF + gid] = acc;
  } else if (gid < 4704) {                              // WQ1[h][cc][j]
    int idx = gid - 608;
    int j = idx & 7, cc = (idx >> 3) & 127, h = idx >> 10;
    const float* a = wq1 + cc * 512 + h * 128;
    const float* b = ((j < 6) ? (wak1 + j * 512) : (wok1 + (j - 6) * 512)) + h * 128;
    float acc = 0.f;
    for (int c = 0; c < 128; c++) acc += a[c] * b[c];
    ws[WQ1_OFF + idx] = acc;
  } else if (gid < 8288) {                              // P_a0[h][i][t]
    int idx = gid - 4704;
    int t = idx & 127, i = (idx >> 7) % 7, h = idx / 896;
    const float* w = wav0 + i * 512 + h * 128;
    const float* p = apw0 + (h * 128) * 128 + t;
    float acc = 0.f;
    for (int c = 0; c < 128; c++) acc += w[c] * p[c * 128];
    ws[PA0_OFF + idx] = acc;
  } else if (gid < 9312) {                              // P_o0[h][i][t]
    int idx = gid - 8288;
    int t = idx & 127, i = (idx >> 7) & 1, h = idx >> 8;
    const float* w = wov0 + i * 512 + h * 128;
    const float* p = opw0 + (h * 128) * 128 + t;
    float acc = 0.f;
    for (int c = 0; c < 128; c++) acc += w[c] * p[c * 128];
    ws[PO0_OFF + idx] = acc;
  } else if (gid < 12896) {                             // P_a1
    int idx = gid - 9312;
    int t = idx & 127, i = (idx >> 7) % 7, h = idx / 896;
    const float* w = wav1 + i * 512 + h * 128;
    const float* p = apw1 + (h * 128) * 128 + t;
    float acc = 0.f;
    for (int c = 0; c < 128; c++) acc += w[c] * p[c * 128];
    ws[PA1_OFF + idx] = acc;
  } else if (gid < 13920) {                             // P_o1
    int idx = gid - 12896;
    int t = idx & 127, i = (idx >> 7) & 1, h = idx >> 8;
    const float* w = wov1 + i * 512 + h * 128;
    const float* p = opw1 + (h * 128) * 128 + t;
    float acc = 0.f;
    for (int c = 0; c < 128; c++) acc += w[c] * p[c * 128];
    ws[PO1_OFF + idx] = acc;
  } else if (gid < 14432) {                             // F1T[i][o]
    int idx = gid - 13920;
    int o2 = idx & 3, i = idx >> 2;
    float acc = 0.f;
    for (int j = 0; j < 128; j++) acc += fpw1[i * 128 + j] * headw[j * 4 + o2];
    ws[F1T_OFF + idx] = acc;
  } else if (gid < 14944) {                             // F1B[i][o]
    int idx = gid - 14432;
    int o2 = idx & 3, i = idx >> 2;
    float acc = 0.f;
    for (int j = 0; j < 128; j++) acc += fpw1[(128 + i) * 128 + j] * headw[j * 4 + o2];
    ws[F1B_OFF + idx] = acc;
  } else if (gid < 15072) {                             // B0[j]
    int j = gid - 14944;
    float acc = fpb0[j];
    for (int c = 0; c < 128; c++)
      acc += apb0[c] * fpw0[c * 128 + j] + opb0[c] * fpw0[(128 + c) * 128 + j];
    ws[B0_OFF + j] = acc;
  } else if (gid < 15200) {                             // bb1[j]
    int j = gid - 15072;
    float acc = fpb1[j];
    for (int c = 0; c < 128; c++)
      acc += apb1[c] * fpw1[c * 128 + j] + opb1[c] * fpw1[(128 + c) * 128 + j];
    ws[BB1_OFF + j] = acc;
  }
}

// ---------------- prep2: AO0, AO1, TB, B1H ----------------
// [0,4608) AO0 | [4608,4752) AO1 | [4752,4784) TB | [4784,4788) B1H
__global__ void prep2(
    const float* __restrict__ fpw0, const float* __restrict__ headw,
    const float* __restrict__ headb, float* __restrict__ ws)
{
  int gid = blockIdx.x * NTH + threadIdx.x;
  if (gid < 4608) {                                     // AO0[h][i][j]
    int j = gid & 127, i = (gid >> 7) % 9, h = gid / 1152;
    float acc = 0.f;
    if (i < 7) {
      const float* P = ws + PA0_OFF + (h * 7 + i) * 128;
      for (int u = 0; u < 128; u++) acc += P[u] * fpw0[u * 128 + j];
    } else {
      const float* P = ws + PO0_OFF + (h * 2 + (i - 7)) * 128;
      for (int u = 0; u < 128; u++) acc += P[u] * fpw0[(128 + u) * 128 + j];
    }
    ws[AO0_OFF + gid] = acc;
  } else if (gid < 4752) {                              // AO1[h][i][o]
    int idx = gid - 4608;
    int o2 = idx & 3, i = (idx >> 2) % 9, h = idx / 36;
    float acc = 0.f;
    if (i < 7) {
      const float* P = ws + PA1_OFF + (h * 7 + i) * 128;
      for (int u = 0; u < 128; u++) acc += P[u] * ws[F1T_OFF + u * 4 + o2];
    } else {
      const float* P = ws + PO1_OFF + (h * 2 + (i - 7)) * 128;
      for (int u = 0; u < 128; u++) acc += P[u] * ws[F1B_OFF + u * 4 + o2];
    }
    ws[AO1_OFF + idx] = acc;
  } else if (gid < 4784) {                              // TB[h][j]
    int idx = gid - 4752;
    int j = idx & 7, h = idx >> 3;
    float acc = 0.f;
    for (int cc = 0; cc < 128; cc++)
      acc += ws[B0_OFF + cc] * ws[WQ1_OFF + h * 1024 + cc * 8 + j];
    ws[TB_OFF + idx] = acc;
  } else if (gid < 4788) {                              // B1H[o]
    int o2 = gid - 4784;
    float acc = headb[o2];
    for (int j = 0; j < 128; j++) acc += ws[BB1_OFF + j] * headw[j * 4 + o2];
    ws[B1H_OFF + o2] = acc;
  }
}

// ---------------- prep3: M = AO0 @ WQ1fold ----------------
__global__ void prep3(float* __restrict__ ws)
{
  int gid = blockIdx.x * NTH + threadIdx.x;
  if (gid < 1152) {                                     // M[t][h*8+j]
    int hj = gid & 31, t = gid >> 5;
    int h = hj >> 3, j = hj & 7;
    float acc = 0.f;
    const float* A = ws + AO0_OFF + t * 128;
    const float* W = ws + WQ1_OFF + h * 1024 + j;
    for (int c = 0; c < 128; c++) acc += A[c] * W[c * 8];
    ws[M_OFF + gid] = acc;
  }
}

// ---------------- main: 1 thread per sample, tables in LDS ----------------
__global__ __launch_bounds__(NTH) void actor_main(
    const float* __restrict__ obs, const float* __restrict__ ws,
    const float* __restrict__ pca0, const float* __restrict__ pco0,
    const float* __restrict__ pca1, const float* __restrict__ pco1,
    float* __restrict__ out, int n)
{
  __shared__ float4 stbl[485];          // 1940 floats of folded tables
  __shared__ float sobs[NTH * 37];
  const int tid = threadIdx.x;
  const int m0 = blockIdx.x * NTH;
  int rows = n - m0; if (rows > NTH) rows = NTH;

  for (int i = tid; i < 485; i += NTH) stbl[i] = ((const float4*)ws)[i];
  {
    const float4* gsrc = (const float4*)(obs + (size_t)m0 * 37);   // 37888B/block: 16B-aligned
    float4* dst = (float4*)sobs;
    int tot = rows * 37, tot4 = tot >> 2;
    for (int i = tid; i < tot4; i += NTH) dst[i] = gsrc[i];
    if (tid < (tot & 3)) sobs[(tot4 << 2) + tid] = obs[(size_t)m0 * 37 + (tot4 << 2) + tid];
  }
  __syncthreads();
  if (tid >= rows) return;

  const float* o = sobs + tid * 37;
  const float scale = 0.17677669529663687f;   // 1/sqrt(32)

  // ---- unpack features ----
  float qf[19];
#pragma unroll
  for (int i = 0; i < 12; i++) qf[i] = o[i];
#pragma unroll
  for (int i = 0; i < 7; i++) qf[12 + i] = o[30 + i];
  float nb[2][6];
#pragma unroll
  for (int k2 = 0; k2 < 2; k2++)
#pragma unroll
    for (int i = 0; i < 6; i++) nb[k2][i] = o[12 + 6 * k2 + i];
  const float nbv6[2] = { o[24], o[25] };
  const float obf[2][2] = { { o[26], o[27] }, { o[28], o[29] } };
  const float ax = o[0], ay = o[1];

  // ---- distances & decay weights ----
  float dista[2], disto[2];
#pragma unroll
  for (int k2 = 0; k2 < 2; k2++) {
    float dx = ax - nb[k2][0], dy = ay - nb[k2][1];
    dista[k2] = sqrtf(dx * dx + dy * dy);
    float ex = ax - obf[k2][0], ey = ay - obf[k2][1];
    disto[k2] = sqrtf(ex * ex + ey * ey);
  }
  const float ca0 = pca0[0], co0 = pco0[0], ca1 = pca1[0], co1 = pco1[0];
  float dwa0[2], dwo0[2], dwa1[2], dwo1[2];
#pragma unroll
  for (int k2 = 0; k2 < 2; k2++) {
    dwa0[k2] = __expf(-ca0 * dista[k2]);
    dwo0[k2] = __expf(-co0 * disto[k2]);
    dwa1[k2] = __expf(-ca1 * dista[k2]);
    dwo1[k2] = __expf(-co1 * disto[k2]);
  }

  // ---- layer 0 query fold: t0[h*8+j] ----
  float t0[32];
#pragma unroll
  for (int z = 0; z < 32; z++) t0[z] = 0.f;
#pragma unroll
  for (int h = 0; h < 4; h++) {
#pragma unroll
    for (int r = 0; r < 19; r++) {
      float q = qf[r];
      float4 w0 = stbl[(h * 19 + r) * 2 + 0];
      float4 w1 = stbl[(h * 19 + r) * 2 + 1];
      t0[h * 8 + 0] += q * w0.x; t0[h * 8 + 1] += q * w0.y;
      t0[h * 8 + 2] += q * w0.z; t0[h * 8 + 3] += q * w0.w;
      t0[h * 8 + 4] += q * w1.x; t0[h * 8 + 5] += q * w1.y;
      t0[h * 8 + 6] += q * w1.z; t0[h * 8 + 7] += q * w1.w;
    }
  }

  // ---- layer 0 attention -> weighted features wff[36] (t = h*9+i) ----
  float wff[36];
#pragma unroll
  for (int h = 0; h < 4; h++) {
    float la[2], lo[2];
#pragma unroll
    for (int k2 = 0; k2 < 2; k2++) {
      float da = t0[h*8+0]*nb[k2][0] + t0[h*8+1]*nb[k2][1] + t0[h*8+2]*nb[k2][2]
               + t0[h*8+3]*nb[k2][3] + t0[h*8+4]*nb[k2][4] + t0[h*8+5]*nb[k2][5];
      la[k2] = da * scale * dwa0[k2];
      float dof = t0[h*8+6]*obf[k2][0] + t0[h*8+7]*obf[k2][1];
      lo[k2] = dof * scale * dwo0[k2];
    }
    float e  = __expf(la[1] - la[0]); float aa1 = e  / (1.f + e);  float aa0 = 1.f - aa1;
    float eo = __expf(lo[1] - lo[0]); float bo1 = eo / (1.f + eo); float bo0 = 1.f - bo1;
#pragma unroll
    for (int i = 0; i < 6; i++) wff[h * 9 + i] = aa0 * nb[0][i] + aa1 * nb[1][i];
    wff[h * 9 + 6] = aa0 * nbv6[0] + aa1 * nbv6[1];
    wff[h * 9 + 7] = bo0 * obf[0][0] + bo1 * obf[1][0];
    wff[h * 9 + 8] = bo0 * obf[0][1] + bo1 * obf[1][1];
  }

  // ---- layer 1 query fold via M: t1f = TB + wff @ M ----
  float t1f[32];
#pragma unroll
  for (int q = 0; q < 8; q++) {
    float4 b = stbl[440 + q];
    t1f[4*q] = b.x; t1f[4*q+1] = b.y; t1f[4*q+2] = b.z; t1f[4*q+3] = b.w;
  }
#pragma unroll
  for (int t = 0; t < 36; t++) {
    float f = wff[t];
#pragma unroll
    for (int q = 0; q < 8; q++) {
      float4 m = stbl[152 + t * 8 + q];
      t1f[4*q]   += f * m.x; t1f[4*q+1] += f * m.y;
      t1f[4*q+2] += f * m.z; t1f[4*q+3] += f * m.w;
    }
  }

  // ---- layer 1 attention ----
  float wf1f[36];
#pragma unroll
  for (int h = 0; h < 4; h++) {
    float la[2], lo[2];
#pragma unroll
    for (int k2 = 0; k2 < 2; k2++) {
      float da = t1f[h*8+0]*nb[k2][0] + t1f[h*8+1]*nb[k2][1] + t1f[h*8+2]*nb[k2][2]
               + t1f[h*8+3]*nb[k2][3] + t1f[h*8+4]*nb[k2][4] + t1f[h*8+5]*nb[k2][5];
      la[k2] = da * scale * dwa1[k2];
      float dof = t1f[h*8+6]*obf[k2][0] + t1f[h*8+7]*obf[k2][1];
      lo[k2] = dof * scale * dwo1[k2];
    }
    float e  = __expf(la[1] - la[0]); float aa1 = e  / (1.f + e);  float aa0 = 1.f - aa1;
    float eo = __expf(lo[1] - lo[0]); float bo1 = eo / (1.f + eo); float bo0 = 1.f - bo1;
#pragma unroll
    for (int i = 0; i < 6; i++) wf1f[h * 9 + i] = aa0 * nb[0][i] + aa1 * nb[1][i];
    wf1f[h * 9 + 6] = aa0 * nbv6[0] + aa1 * nbv6[1];
    wf1f[h * 9 + 7] = bo0 * obf[0][0] + bo1 * obf[1][0];
    wf1f[h * 9 + 8] = bo0 * obf[0][1] + bo1 * obf[1][1];
  }

  // ---- output: B1H + wf1f @ AO1 ----
  float4 acc = stbl[484];
#pragma unroll
  for (int t = 0; t < 36; t++) {
    float f = wf1f[t];
    float4 w = stbl[448 + t];
    acc.x += f * w.x; acc.y += f * w.y; acc.z += f * w.z; acc.w += f * w.w;
  }
  ((float4*)out)[m0 + tid] = acc;
}

extern "C" void kernel_launch(void* const* d_in, const int* in_sizes, int n_in,
                              void* d_out, int out_size, void* d_ws, size_t ws_size,
                              hipStream_t stream)
{
  const float* obs  = (const float*)d_in[0];
  const float* wq0  = (const float*)d_in[1];
  const float* wak0 = (const float*)d_in[2];
  const float* wav0 = (const float*)d_in[3];
  const float* wok0 = (const float*)d_in[4];
  const float* wov0 = (const float*)d_in[5];
  const float* apw0 = (const float*)d_in[6];
  const float* apb0 = (const float*)d_in[7];
  const float* opw0 = (const float*)d_in[8];
  const float* opb0 = (const float*)d_in[9];
  const float* fpw0 = (const float*)d_in[10];
  const float* fpb0 = (const float*)d_in[11];
  const float* ca0  = (const float*)d_in[12];
  const float* co0  = (const float*)d_in[13];
  const float* wq1  = (const float*)d_in[14];
  const float* wak1 = (const float*)d_in[15];
  const float* wav1 = (const float*)d_in[16];
  const float* wok1 = (const float*)d_in[17];
  const float* wov1 = (const float*)d_in[18];
  const float* apw1 = (const float*)d_in[19];
  const float* apb1 = (const float*)d_in[20];
  const float* opw1 = (const float*)d_in[21];
  const float* opb1 = (const float*)d_in[22];
  const float* fpw1 = (const float*)d_in[23];
  const float* fpb1 = (const float*)d_in[24];
  const float* ca1  = (const float*)d_in[25];
  const float* co1  = (const float*)d_in[26];
  const float* headw = (const float*)d_in[27];
  const float* headb = (const float*)d_in[28];
  float* ws = (float*)d_ws;
  int n = in_sizes[0] / 37;

  prep1<<<(15200 + NTH - 1) / NTH, NTH, 0, stream>>>(
      wq0, wak0, wok0, wq1, wak1, wok1,
      wav0, apw0, wov0, opw0, wav1, apw1, wov1, opw1,
      fpw1, headw, fpw0, fpb0, apb0, opb0, fpb1, apb1, opb1, ws);
  prep2<<<(4788 + NTH - 1) / NTH, NTH, 0, stream>>>(fpw0, headw, headb, ws);
  prep3<<<(1152 + NTH - 1) / NTH, NTH, 0, stream>>>(ws);
  actor_main<<<(n + NTH - 1) / NTH, NTH, 0, stream>>>(
      obs, ws, ca0, co0, ca1, co1, (float*)d_out, n);
}